// Round 2
// baseline (121.278 us; speedup 1.0000x reference)
//
#include <hip/hip_runtime.h>

// QueryAndGroup: ball query (first 32 idx within radius, index order, padded
// with first hit) + grouped_xyz (xyz[idx]-center) + grouped feature gather.
// Shapes: xyz (8,16384,3) f32, new_xyz (8,1024,3) f32, features (8,64,16384) f32
// Out: (8, 3+64, 1024, 32) f32.
//
// R7 = R6 with the compile fix: nontemporal_store needs a NATIVE clang vector
// (ext_vector_type), not HIP's float4 wrapper.
//  - gather: async global_load_lds (width 16) staging — no VGPR round trip;
//    ALL idx int4 prefetched to registers before the barrier (overlapped with
//    stage); nontemporal v4f output stores (don't evict idx/feats from L2).
//  - query: v_mbcnt prefix-count instead of popcll(m&below); wave-private
//    sidx needs only lgkmcnt(0), not __syncthreads — waves decoupled.

#define BB 8
#define NN 16384
#define SS 1024
#define CC 64
#define NSAMP 32
#define OUTCH (3 + CC)

// float(0.04) to match numpy's weak-scalar promotion (NOT 0.2f*0.2f).
#define R2 0.04f

typedef float v4f __attribute__((ext_vector_type(4)));

__device__ __forceinline__ void load_lds16(const float* g, float* l) {
    __builtin_amdgcn_global_load_lds(
        (const __attribute__((address_space(1))) unsigned int*)g,
        (__attribute__((address_space(3))) unsigned int*)l, 16, 0, 0);
}

// ---------------- kernel A: ball query ----------------
// 4 waves/block, one query per wave, 512-pt chunks (loads batched ahead of
// the ballot phase -> one latency per chunk).
__global__ __launch_bounds__(256) void query_kernel(
    const float* __restrict__ xyz,      // (B,N,3)
    const float* __restrict__ new_xyz,  // (B,S,3)
    int* __restrict__ idxq,             // ws: (B*S,32)
    float* __restrict__ out)            // (B,67,S,32)
{
    __shared__ int sidx[4][NSAMP];

    const int t    = threadIdx.x;
    const int wave = t >> 6;
    const int lane = t & 63;
    const int q    = blockIdx.x * 4 + wave;   // 0..8191
    const int b    = q >> 10;
    const int s    = q & (SS - 1);

    const float* xb = xyz + (size_t)b * NN * 3;
    const float* xl = xb + (size_t)lane * 3;   // per-lane base: addr = s_base + lane*12
    const float qx = new_xyz[((size_t)b * SS + s) * 3 + 0];
    const float qy = new_xyz[((size_t)b * SS + s) * 3 + 1];
    const float qz = new_xyz[((size_t)b * SS + s) * 3 + 2];

    int count = 0;
    for (int base = 0; base < NN; base += 512) {
        float d2[8];
        #pragma unroll
        for (int j = 0; j < 8; ++j) {
            const float* p = xl + (size_t)(base + j * 64) * 3;
            const float dx = qx - p[0];
            const float dy = qy - p[1];
            const float dz = qz - p[2];
            // numpy order, no FMA contraction
            d2[j] = __fadd_rn(__fadd_rn(__fmul_rn(dx, dx),
                                        __fmul_rn(dy, dy)),
                              __fmul_rn(dz, dz));
        }
        #pragma unroll
        for (int j = 0; j < 8; ++j) {
            const bool within = d2[j] < R2;
            const unsigned long long m = __ballot(within);
            if (within) {
                // prefix popcount below lane: 2 VALU (v_mbcnt_lo/hi)
                const int pre = (int)__builtin_amdgcn_mbcnt_hi(
                    (unsigned)(m >> 32),
                    __builtin_amdgcn_mbcnt_lo((unsigned)m, 0u));
                const int pos = count + pre;
                if (pos < NSAMP) sidx[wave][pos] = base + j * 64 + lane;
            }
            count += __popcll(m);   // uniform -> s_bcnt1
        }
        if (count >= NSAMP) break;   // wave-uniform
    }
    // sidx[wave][*] is wave-private: DS completion is enough, no block barrier
    // (decouples the 4 waves: short-scan waves store out early).
    asm volatile("s_waitcnt lgkmcnt(0)" ::: "memory");
    const int cnt = count < NSAMP ? count : NSAMP;
    const int first = (cnt > 0) ? sidx[wave][0] : 0;
    if (lane < NSAMP && lane >= cnt) sidx[wave][lane] = first;
    asm volatile("s_waitcnt lgkmcnt(0)" ::: "memory");

    if (lane < NSAMP) {
        const int k = lane;
        const int idx = sidx[wave][k];
        idxq[(size_t)q * NSAMP + k] = idx;   // normal store: re-read by gather
        // grouped_xyz -> out channels 0..2 (128B coalesced per channel)
        const float gx = xb[idx * 3 + 0] - qx;
        const float gy = xb[idx * 3 + 1] - qy;
        const float gz = xb[idx * 3 + 2] - qz;
        const size_t o = (((size_t)b * OUTCH + 0) * SS + s) * NSAMP + k;
        __builtin_nontemporal_store(gx, out + o + 0 * (size_t)SS * NSAMP);
        __builtin_nontemporal_store(gy, out + o + 1 * (size_t)SS * NSAMP);
        __builtin_nontemporal_store(gz, out + o + 2 * (size_t)SS * NSAMP);
    }
}

// ---------------- kernel B: row-in-LDS gather ----------------
// one block per (b,c): async-stage feats[b,c,:] (64KB) into LDS with
// global_load_lds while prefetching ALL idx int4 into registers; after one
// vmcnt(0)+barrier the gather loop is pure LDS-read + coalesced NT stores.
__global__ __launch_bounds__(512, 4) void gather_kernel(
    const float* __restrict__ feats,    // (B,C,N)
    const int*   __restrict__ idxq,     // (B*S,32)
    float* __restrict__ out)            // (B,67,S,32)
{
    __shared__ float row[NN];           // 64 KB -> 2 blocks/CU

    const int c = blockIdx.x;           // 0..63
    const int b = blockIdx.y;           // 0..7
    const int t = threadIdx.x;          // 0..511

    // async stage: lane-linear LDS dest (wave base + lane*16), 8 x 16B/thread
    const float* fr = feats + ((size_t)b * CC + c) * NN;
    #pragma unroll
    for (int i = 0; i < 8; ++i) {
        const int o = (i * 512 + t) * 4;
        load_lds16(fr + o, row + o);
    }

    // idx prefetch into registers (64 VGPRs), overlapped with the stage
    const int k4 = (t & 7) * 4;
    const int s0 = t >> 3;              // 0..63
    const int* ib = idxq + (size_t)b * SS * NSAMP;
    int4 id[16];
    #pragma unroll
    for (int it = 0; it < 16; ++it)
        id[it] = *(const int4*)(ib + (size_t)(it * 64 + s0) * NSAMP + k4);

    asm volatile("s_waitcnt vmcnt(0)" ::: "memory");
    __syncthreads();

    float* ob = out + (((size_t)b * OUTCH + 3 + c) * SS) * NSAMP;
    #pragma unroll
    for (int it = 0; it < 16; ++it) {
        const int s = it * 64 + s0;
        v4f v;
        v.x = row[id[it].x];
        v.y = row[id[it].y];
        v.z = row[id[it].z];
        v.w = row[id[it].w];
        __builtin_nontemporal_store(v, (v4f*)(ob + (size_t)s * NSAMP + k4));
    }
}

// ---------------- fallback: R1 fused kernel (if ws too small) ----------------
__global__ __launch_bounds__(64) void qg_fused(
    const float* __restrict__ xyz, const float* __restrict__ new_xyz,
    const float* __restrict__ feats, float* __restrict__ out)
{
    const int bs   = blockIdx.x;
    const int b    = bs >> 10;
    const int s    = bs & (SS - 1);
    const int lane = threadIdx.x;

    const float* xb = xyz + (size_t)b * NN * 3;
    const float qx = new_xyz[((size_t)b * SS + s) * 3 + 0];
    const float qy = new_xyz[((size_t)b * SS + s) * 3 + 1];
    const float qz = new_xyz[((size_t)b * SS + s) * 3 + 2];

    __shared__ int sidx[NSAMP];
    int count = 0;
    for (int base = 0; base < NN; base += 64) {
        const int i = base + lane;
        const float dx = qx - xb[i * 3 + 0];
        const float dy = qy - xb[i * 3 + 1];
        const float dz = qz - xb[i * 3 + 2];
        const float d2 = __fadd_rn(__fadd_rn(__fmul_rn(dx, dx),
                                             __fmul_rn(dy, dy)),
                                   __fmul_rn(dz, dz));
        const bool within = d2 < R2;
        const unsigned long long m = __ballot(within);
        if (within) {
            const int pos = count + __popcll(m & ((1ull << lane) - 1ull));
            if (pos < NSAMP) sidx[pos] = i;
        }
        count += __popcll(m);
        if (count >= NSAMP) break;
    }
    __syncthreads();
    const int cnt = count < NSAMP ? count : NSAMP;
    const int first = (cnt > 0) ? sidx[0] : 0;
    if (lane < NSAMP && lane >= cnt) sidx[lane] = first;
    __syncthreads();

    const int k    = lane & 31;
    const int half = lane >> 5;
    const int idx  = sidx[k];
    const size_t obase = (((size_t)b * OUTCH + 0) * SS + s) * NSAMP + k;
    if (half == 0) {
        out[obase + 0 * (size_t)SS * NSAMP] = xb[idx * 3 + 0] - qx;
        out[obase + 1 * (size_t)SS * NSAMP] = xb[idx * 3 + 1] - qy;
        out[obase + 2 * (size_t)SS * NSAMP] = xb[idx * 3 + 2] - qz;
    }
    const float* fb = feats + (size_t)b * CC * NN;
    const size_t fo = (((size_t)b * OUTCH + 3) * SS + s) * NSAMP + k;
    for (int cch = half; cch < CC; cch += 2) {
        out[fo + (size_t)cch * SS * NSAMP] = fb[(size_t)cch * NN + idx];
    }
}

extern "C" void kernel_launch(void* const* d_in, const int* in_sizes, int n_in,
                              void* d_out, int out_size, void* d_ws, size_t ws_size,
                              hipStream_t stream) {
    const float* xyz     = (const float*)d_in[0];
    const float* new_xyz = (const float*)d_in[1];
    const float* feats   = (const float*)d_in[2];
    float* out           = (float*)d_out;

    const size_t idx_bytes = (size_t)BB * SS * NSAMP * sizeof(int);     // 1 MB

    if (ws_size >= idx_bytes) {
        int* idxq = (int*)d_ws;
        query_kernel<<<2048, 256, 0, stream>>>(xyz, new_xyz, idxq, out);
        gather_kernel<<<dim3(CC, BB), 512, 0, stream>>>(feats, idxq, out);
    } else {
        qg_fused<<<BB * SS, 64, 0, stream>>>(xyz, new_xyz, feats, out);
    }
}